// Round 4
// baseline (637.652 us; speedup 1.0000x reference)
//
#include <hip/hip_runtime.h>
#include <stdint.h>

// ---------------------------------------------------------------------------
// GINEncoder: 2x GINEConv(eps=0, MLP 128->128->128, edge_lin 32->128) + head.
//   1. CSR by dst (hist + two-level scan + scatter), then a FLAT CHUNK LIST:
//      cmeta[c] = {edge_base, (node<<5)|rem}; every node has >=1 chunk
//      (deg-0 -> rem=0, all lanes sentinel). Wave ranges balanced by chunk
//      count, aligned to node boundaries (cws).
//   2. agg_mfma (R11): 2-deep ping-pong software pipeline over chunks:
//      pack/cmeta fetched 2 ahead, xpk/ea gathers issued 1 ahead into the
//      alternate register slot, MFMA consumes the current slot. No register
//      rotation (explicit A/B macros, compile-time indices only). we-fragments
//      live in an 8KB LDS tile to keep VGPR<=128 (4 waves/SIMD).
//      x[src] gather folded into MFMA via identity-B fragments (xpk bf16
//      hi/lo, be folded in; sentinel row N = -29958 kills pad lanes in relu).
//   3. mlp2_mfma: fused GEMM pairs (bf16x3 MFMA, fp32 acc) via per-wave LDS.
// edge_index is int64 in the reference but harness passes int32.
// ---------------------------------------------------------------------------

#define ND 128
#define ED 32

typedef __attribute__((ext_vector_type(8))) short short8;
typedef __attribute__((ext_vector_type(4))) float f32x4;

__device__ inline unsigned short bf16_hi(float f) {
    union { float f; unsigned u; } v;
    v.f = f;
    return (unsigned short)(v.u >> 16);  // truncation; residual captured by lo
}
__device__ inline float bf16_f(unsigned short h) {
    union { unsigned u; float f; } v;
    v.u = ((unsigned)h) << 16;
    return v.f;
}

__device__ inline int cc_of(int d) { return d ? (d + 15) >> 4 : 1; }

__global__ __launch_bounds__(256) void zero_kernel(int* __restrict__ p, int n) {
    int i = blockIdx.x * blockDim.x + threadIdx.x;
    if (i < n) p[i] = 0;
}

__global__ __launch_bounds__(256) void hist_kernel(const int* __restrict__ ei,
                                                   int* __restrict__ counts, int E) {
    int i = blockIdx.x * blockDim.x + threadIdx.x;
    if (i < E) atomicAdd(&counts[ei[E + i]], 1);
}

// ---- two-level parallel scan over counts[N] (plain + chunk-count versions) ----
__global__ __launch_bounds__(256) void bsum_kernel(const int* __restrict__ counts,
                                                   int* __restrict__ bsum, int N) {
    __shared__ int s[256];
    int t = threadIdx.x;
    int i = blockIdx.x * 256 + t;
    s[t] = (i < N) ? counts[i] : 0;
    __syncthreads();
#pragma unroll
    for (int off = 128; off > 0; off >>= 1) {
        if (t < off) s[t] += s[t + off];
        __syncthreads();
    }
    if (t == 0) bsum[blockIdx.x] = s[0];
}

__global__ __launch_bounds__(256) void cbsum_kernel(const int* __restrict__ counts,
                                                    int* __restrict__ bsum, int N) {
    __shared__ int s[256];
    int t = threadIdx.x;
    int i = blockIdx.x * 256 + t;
    s[t] = (i < N) ? cc_of(counts[i]) : 0;
    __syncthreads();
#pragma unroll
    for (int off = 128; off > 0; off >>= 1) {
        if (t < off) s[t] += s[t + off];
        __syncthreads();
    }
    if (t == 0) bsum[blockIdx.x] = s[0];
}

__global__ __launch_bounds__(256) void scan_bsums(const int* __restrict__ bsum,
                                                  int* __restrict__ bofs,
                                                  int* __restrict__ total_out, int NB) {
    __shared__ int s[256];
    int t = threadIdx.x;
    int chunk = (NB + 255) >> 8;
    int lo = min(t * chunk, NB);
    int hi = min(lo + chunk, NB);
    int sum = 0;
    for (int i = lo; i < hi; ++i) sum += bsum[i];
    s[t] = sum;
    __syncthreads();
    for (int off = 1; off < 256; off <<= 1) {
        int v = (t >= off) ? s[t - off] : 0;
        __syncthreads();
        s[t] += v;
        __syncthreads();
    }
    int pre = (t == 0) ? 0 : s[t - 1];
    for (int i = lo; i < hi; ++i) {
        bofs[i] = pre;
        pre += bsum[i];
    }
    if (t == 255) *total_out = s[255];
}

__global__ __launch_bounds__(256) void expand_kernel(const int* __restrict__ counts,
                                                     const int* __restrict__ bofs,
                                                     int* __restrict__ row_start,
                                                     int* __restrict__ woff, int N) {
    __shared__ int s[256];
    int t = threadIdx.x;
    int i = blockIdx.x * 256 + t;
    int c = (i < N) ? counts[i] : 0;
    s[t] = c;
    __syncthreads();
    for (int off = 1; off < 256; off <<= 1) {
        int v = (t >= off) ? s[t - off] : 0;
        __syncthreads();
        s[t] += v;
        __syncthreads();
    }
    if (i < N) {
        int pre = bofs[blockIdx.x] + s[t] - c;  // exclusive
        row_start[i] = pre;
        woff[i] = pre;
    }
}

__global__ __launch_bounds__(256) void cexpand_kernel(const int* __restrict__ counts,
                                                      const int* __restrict__ bofs,
                                                      int* __restrict__ cofs, int N) {
    __shared__ int s[256];
    int t = threadIdx.x;
    int i = blockIdx.x * 256 + t;
    int c = (i < N) ? cc_of(counts[i]) : 0;
    s[t] = c;
    __syncthreads();
    for (int off = 1; off < 256; off <<= 1) {
        int v = (t >= off) ? s[t - off] : 0;
        __syncthreads();
        s[t] += v;
        __syncthreads();
    }
    if (i < N) cofs[i] = bofs[blockIdx.x] + s[t] - c;  // exclusive
}

__global__ __launch_bounds__(256) void scatter_kernel(const int* __restrict__ ei,
                                                      int* __restrict__ woff,
                                                      int2* __restrict__ pack, int E) {
    int i = blockIdx.x * blockDim.x + threadIdx.x;
    if (i < E) {
        int d = ei[E + i];
        int p = atomicAdd(&woff[d], 1);
        pack[p] = make_int2(ei[i], i);  // {src, eid}
    }
}

// Flat chunk list: per node, chunks {base, (v<<5)|rem}; deg-0 -> one rem=0 chunk.
__global__ __launch_bounds__(256) void cfill_kernel(const int* __restrict__ row_start,
                                                    const int* __restrict__ cofs,
                                                    int2* __restrict__ cmeta, int N) {
    int v = blockIdx.x * 256 + threadIdx.x;
    if (v >= N) return;
    int beg = row_start[v], end = row_start[v + 1];
    int deg = end - beg;
    int nc = cc_of(deg);
    int co = cofs[v];
    for (int j = 0; j < nc; ++j) {
        int rem = deg - j * 16;
        rem = rem > 16 ? 16 : (rem < 0 ? 0 : rem);
        cmeta[co + j] = make_int2(beg + j * 16, (v << 5) | rem);
    }
}

// Chunk-balanced wave ranges aligned to node boundaries: cws[w] = cofs[v*],
// v* = min v : cofs[v+1] > w*NC/NW.
__global__ __launch_bounds__(256) void cwrange_kernel(const int* __restrict__ cofs,
                                                      int* __restrict__ cws,
                                                      int N, int NW) {
    int w = blockIdx.x * 256 + threadIdx.x;
    if (w > NW) return;
    int NC = cofs[N];
    if (w == 0) { cws[0] = 0; return; }
    if (w == NW) { cws[NW] = NC; return; }
    long long T = (long long)w * NC / NW;
    int lo = 0, hi = N - 1;
    while (lo < hi) {
        int mid = (lo + hi) >> 1;
        if (cofs[mid + 1] > T) hi = mid; else lo = mid + 1;
    }
    cws[w] = cofs[lo];
}

// Split 6 weight matrices [128,128] into bf16 hi/lo, MFMA B-fragment order:
// chunk c = nt*4+ks; lane l holds B[k=ks*32+(l>>4)*8+j][n=nt*16+(l&15)], j=0..7.
__global__ __launch_bounds__(256) void wprep_kernel(
    const float* __restrict__ w0, const float* __restrict__ w1,
    const float* __restrict__ w2, const float* __restrict__ w3,
    const float* __restrict__ w4, const float* __restrict__ w5,
    unsigned short* __restrict__ hi, unsigned short* __restrict__ lo) {
    int t = blockIdx.x * blockDim.x + threadIdx.x;  // 0..2047
    const float* W;
    switch (blockIdx.y) {
        case 0: W = w0; break;
        case 1: W = w1; break;
        case 2: W = w2; break;
        case 3: W = w3; break;
        case 4: W = w4; break;
        default: W = w5; break;
    }
    unsigned short* dh = hi + (size_t)blockIdx.y * 16384;
    unsigned short* dl = lo + (size_t)blockIdx.y * 16384;
    int c = t >> 6, l = t & 63;
    int nt = c >> 2, ks = c & 3;
    int n = nt * 16 + (l & 15);
    int kb = ks * 32 + ((l >> 4) << 3);
#pragma unroll
    for (int j = 0; j < 8; ++j) {
        float f = W[(size_t)(kb + j) * ND + n];
        unsigned short h = bf16_hi(f);
        dh[((size_t)c * 64 + l) * 8 + j] = h;
        dl[((size_t)c * 64 + l) * 8 + j] = bf16_hi(f - bf16_f(h));
    }
}

// Prep we [32,128] (2 matrices) into bf16-hi B-fragments: chunk = nt (8);
// lane l holds we[k=(l>>4)*8+j][n=nt*16+(l&15)].
__global__ __launch_bounds__(256) void wprep_we(const float* __restrict__ w0,
                                                const float* __restrict__ w1,
                                                unsigned short* __restrict__ hi) {
    int t = threadIdx.x;
    int c = (blockIdx.x << 2) + (t >> 6);  // nt 0..7
    int l = t & 63;
    const float* W = blockIdx.y ? w1 : w0;
    unsigned short* dh = hi + (size_t)blockIdx.y * 4096;
    int n = c * 16 + (l & 15);
    int kb = (l >> 4) << 3;
#pragma unroll
    for (int j = 0; j < 8; ++j)
        dh[((size_t)c * 64 + l) * 8 + j] = bf16_hi(W[(size_t)(kb + j) * ND + n]);
}

// Pack node features [N,128] fp32 -> bf16 hi/lo A-fragment granules, with the
// layer bias be folded in: packs (x[v][col] + be[col]).
// Granule g = kc*4 + quad covers elements [g*8, g*8+8); layout per row:
// [kc(4)][quad(4)][8 hi bf16 = 16B][8 lo bf16 = 16B] = 512B/row.
// Row N is the pad sentinel: -29958 so relu(msg) == 0 for padded lanes.
__global__ __launch_bounds__(256) void xprep_kernel(const float* __restrict__ X,
                                                    const float* __restrict__ be,
                                                    unsigned short* __restrict__ xpk,
                                                    int N) {
    int t = blockIdx.x * 256 + threadIdx.x;
    int total = (N + 1) * 16;
    if (t >= total) return;
    int v = t >> 4, g = t & 15;
    short8 h, l;
    if (v < N) {
        const float4* p = (const float4*)(X + (size_t)v * ND + g * 8);
        float4 a0 = p[0], a1 = p[1];
        float f[8] = {a0.x, a0.y, a0.z, a0.w, a1.x, a1.y, a1.z, a1.w};
#pragma unroll
        for (int j = 0; j < 8; ++j) {
            float fv = f[j] + be[g * 8 + j];
            unsigned short hh = bf16_hi(fv);
            h[j] = (short)hh;
            l[j] = (short)bf16_hi(fv - bf16_f(hh));
        }
    } else {
#pragma unroll
        for (int j = 0; j < 8; ++j) {
            h[j] = (short)0xC6EA;  // bf16(-29958)
            l[j] = 0;
        }
    }
    unsigned short* dst = xpk + (size_t)t * 16;
    *(short8*)dst = h;
    *(short8*)(dst + 8) = l;
}

// ---- agg pipeline macros (compile-time indices only; see rule #20) ----
#define GATHER(S, MM, PKK)                                                      \
    {                                                                           \
        int rem_ = (MM).y & 31;                                                 \
        int s_ = (m < rem_) ? (PKK).x : N;                                      \
        const unsigned short* xr_ = xpk + ((size_t)s_ * 16 + quad) * 16;        \
        _Pragma("unroll") for (int kc = 0; kc < 4; ++kc) {                      \
            xh_##S[kc] = *(const short8*)(xr_ + kc * 64);                       \
            xl_##S[kc] = *(const short8*)(xr_ + kc * 64 + 8);                   \
        }                                                                       \
        const float4* ar_ =                                                     \
            (const float4*)(edge_attr + (size_t)(PKK).y * ED + quad * 8);       \
        ea_##S[0] = ar_[0];                                                     \
        ea_##S[1] = ar_[1];                                                     \
    }

#define COMPUTE(S)                                                              \
    {                                                                           \
        float af_[8] = {ea_##S[0].x, ea_##S[0].y, ea_##S[0].z, ea_##S[0].w,     \
                        ea_##S[1].x, ea_##S[1].y, ea_##S[1].z, ea_##S[1].w};    \
        short8 ah_, al_;                                                        \
        _Pragma("unroll") for (int j = 0; j < 8; ++j) {                         \
            unsigned short h_ = bf16_hi(af_[j]);                                \
            ah_[j] = (short)h_;                                                 \
            al_[j] = (short)bf16_hi(af_[j] - bf16_f(h_));                       \
        }                                                                       \
        _Pragma("unroll") for (int nt = 0; nt < 8; ++nt) {                      \
            short8 bh_ = *(const short8*)(bhs + ((size_t)nt * 64 + lane) * 8);  \
            f32x4 a_ = {0.f, 0.f, 0.f, 0.f};                                    \
            a_ = __builtin_amdgcn_mfma_f32_16x16x32_bf16(ah_, bh_, a_, 0, 0, 0);\
            a_ = __builtin_amdgcn_mfma_f32_16x16x32_bf16(al_, bh_, a_, 0, 0, 0);\
            a_ = __builtin_amdgcn_mfma_f32_16x16x32_bf16(xh_##S[nt >> 1],       \
                                                         idf[nt & 1], a_, 0, 0, 0); \
            a_ = __builtin_amdgcn_mfma_f32_16x16x32_bf16(xl_##S[nt >> 1],       \
                                                         idf[nt & 1], a_, 0, 0, 0); \
            _Pragma("unroll") for (int r = 0; r < 4; ++r)                       \
                part[nt] += fmaxf(a_[r], 0.f);                                  \
        }                                                                       \
    }

#define FLUSHCHK(C_, NODEN_)                                                    \
    if ((C_) == cap || (NODEN_) != curv) {                                      \
        _Pragma("unroll") for (int nt = 0; nt < 8; ++nt) {                      \
            float p_ = part[nt];                                                \
            p_ += __shfl_xor(p_, 16, 64);                                       \
            p_ += __shfl_xor(p_, 32, 64);                                       \
            part[nt] = p_;                                                      \
        }                                                                       \
        float o0_ = quad == 0 ? part[0] : quad == 1 ? part[2]                   \
                  : quad == 2 ? part[4] : part[6];                              \
        float o1_ = quad == 0 ? part[1] : quad == 1 ? part[3]                   \
                  : quad == 2 ? part[5] : part[7];                              \
        hout[(size_t)curv * ND + col0] = res0 + o0_;                            \
        hout[(size_t)curv * ND + col1] = res1 + o1_;                            \
        if ((C_) != cap) {                                                      \
            curv = (NODEN_);                                                    \
            res0 = xin[(size_t)curv * ND + col0];                               \
            res1 = xin[(size_t)curv * ND + col1];                               \
            _Pragma("unroll") for (int nt = 0; nt < 8; ++nt) part[nt] = 0.f;    \
        }                                                                       \
    }

// Node-centric MFMA aggregation, 2-deep ping-pong pipelined over flat chunks.
// h[v] = x[v] + sum_{e: dst=v} relu((x[src_e]+be) + ea_e @ we)
__global__ __launch_bounds__(256, 4) void agg_mfma(
    const float* __restrict__ xin, const float* __restrict__ edge_attr,
    const unsigned short* __restrict__ xpk, const unsigned short* __restrict__ bfh,
    const int* __restrict__ cws, const int2* __restrict__ cmeta,
    const int2* __restrict__ pack, float* __restrict__ hout, int N, int E) {
    __shared__ unsigned short bhs[8 * 64 * 8];  // we B-fragments, wave-shared
    int lane = threadIdx.x & 63;
    int wave = threadIdx.x >> 6;
    int m = lane & 15;
    int quad = lane >> 4;

    {   // fill we-fragment LDS (each wave fills 2 nt slots)
        int nt0 = wave * 2;
        *(short8*)(bhs + ((size_t)nt0 * 64 + lane) * 8) =
            *(const short8*)(bfh + ((size_t)nt0 * 64 + lane) * 8);
        *(short8*)(bhs + ((size_t)(nt0 + 1) * 64 + lane) * 8) =
            *(const short8*)(bfh + ((size_t)(nt0 + 1) * 64 + lane) * 8);
    }
    __syncthreads();

    int gw = (blockIdx.x * blockDim.x + threadIdx.x) >> 6;
    int c_lo = cws[gw], c_hi = cws[gw + 1];
    if (c_lo >= c_hi) return;
    int cap = c_hi - 1;

    // identity B-fragments: for tile parity q, B[k'=quad*8+j][n'=m] = (k'==q*16+m)
    short8 idf[2];
#pragma unroll
    for (int q = 0; q < 2; ++q)
#pragma unroll
        for (int j = 0; j < 8; ++j)
            idf[q][j] = (quad * 8 + j == q * 16 + m) ? (short)0x3F80 : (short)0;

    int col0 = quad * 32 + m;
    int col1 = col0 + 16;

    // ---- pipeline prologue: meta/pack 3 deep, gathers 1 deep ----
    int2 m0 = cmeta[c_lo];
    int2 m1 = cmeta[min(c_lo + 1, cap)];
    int2 m2 = cmeta[min(c_lo + 2, cap)];
    int2 pk0 = pack[min(m0.x + m, E - 1)];
    int2 pk1 = pack[min(m1.x + m, E - 1)];
    int2 pk2 = pack[min(m2.x + m, E - 1)];

    short8 xh_a[4], xl_a[4]; float4 ea_a[2];
    short8 xh_b[4], xl_b[4]; float4 ea_b[2];

    GATHER(a, m0, pk0);
    int curv = m0.y >> 5;
    float res0 = xin[(size_t)curv * ND + col0];
    float res1 = xin[(size_t)curv * ND + col1];
    float part[8];
#pragma unroll
    for (int nt = 0; nt < 8; ++nt) part[nt] = 0.f;

    int c = c_lo;
    while (true) {
        // compute slot a (chunk c); issue slot b (chunk c+1)
        {
            int noden = m1.y >> 5;
            GATHER(b, m1, pk1);
            m1 = m2; pk1 = pk2;
            m2 = cmeta[min(c + 3, cap)];
            pk2 = pack[min(m2.x + m, E - 1)];
            COMPUTE(a);
            FLUSHCHK(c, noden);
        }
        ++c;
        if (c >= c_hi) break;

        // compute slot b (chunk c); issue slot a (chunk c+1)
        {
            int noden = m1.y >> 5;
            GATHER(a, m1, pk1);
            m1 = m2; pk1 = pk2;
            m2 = cmeta[min(c + 3, cap)];
            pk2 = pack[min(m2.x + m, E - 1)];
            COMPUTE(b);
            FLUSHCHK(c, noden);
        }
        ++c;
        if (c >= c_hi) break;
    }
}

// Fused pair of GEMMs: C = maybe_relu2( relu(A@W1+b1) @ W2 + b2 ).
// Wave = 16 rows; intermediate goes through a per-wave LDS tile (132-pad rows).
#define LP 132  // padded LDS row stride (floats); 132*4B keeps 16B alignment
__global__ __launch_bounds__(256, 4) void mlp2_mfma(
    const float* __restrict__ A,
    const unsigned short* __restrict__ w1h, const unsigned short* __restrict__ w1l,
    const float* __restrict__ b1,
    const unsigned short* __restrict__ w2h, const unsigned short* __restrict__ w2l,
    const float* __restrict__ b2,
    float* __restrict__ C, int N, int relu2) {
    __shared__ float tile[4][16 * LP];
    int lane = threadIdx.x & 63;
    int wave = threadIdx.x >> 6;
    int gw = blockIdx.x * 4 + wave;
    int m0 = gw * 16;
    if (m0 >= N) return;
    int m = lane & 15;
    int quad = lane >> 4;
    float* T = tile[wave];

    // ---- stage 1: load A rows, split hi/lo ----
    int row = m0 + m;
    bool rok = row < N;
    short8 ah[4], al[4];
#pragma unroll
    for (int ks = 0; ks < 4; ++ks) {
        float f[8];
        if (rok) {
            const float4* p = (const float4*)(A + (size_t)row * ND + ks * 32 + quad * 8);
            float4 a0 = p[0], a1 = p[1];
            f[0] = a0.x; f[1] = a0.y; f[2] = a0.z; f[3] = a0.w;
            f[4] = a1.x; f[5] = a1.y; f[6] = a1.z; f[7] = a1.w;
        } else {
#pragma unroll
            for (int j = 0; j < 8; ++j) f[j] = 0.f;
        }
#pragma unroll
        for (int j = 0; j < 8; ++j) {
            unsigned short hh = bf16_hi(f[j]);
            ah[ks][j] = (short)hh;
            al[ks][j] = (short)bf16_hi(f[j] - bf16_f(hh));
        }
    }

    // GEMM1 -> bias + relu -> LDS tile (C/D layout: col=lane&15, row=quad*4+r)
#pragma unroll
    for (int nt = 0; nt < 8; ++nt) {
        f32x4 acc = {0.f, 0.f, 0.f, 0.f};
#pragma unroll
        for (int ks = 0; ks < 4; ++ks) {
            size_t off = ((size_t)(nt * 4 + ks) * 64 + lane) * 8;
            short8 bh = *(const short8*)(w1h + off);
            short8 bl = *(const short8*)(w1l + off);
            acc = __builtin_amdgcn_mfma_f32_16x16x32_bf16(ah[ks], bh, acc, 0, 0, 0);
            acc = __builtin_amdgcn_mfma_f32_16x16x32_bf16(al[ks], bh, acc, 0, 0, 0);
            acc = __builtin_amdgcn_mfma_f32_16x16x32_bf16(ah[ks], bl, acc, 0, 0, 0);
        }
        float bv = b1[nt * 16 + m];
#pragma unroll
        for (int r = 0; r < 4; ++r) {
            float o = acc[r] + bv;
            o = o > 0.f ? o : 0.f;
            T[(quad * 4 + r) * LP + nt * 16 + m] = o;
        }
    }

    // ---- stage 2: rows from LDS as A-fragments (same wave -> lgkmcnt wait) ----
    short8 ch[4], cl[4];
#pragma unroll
    for (int ks = 0; ks < 4; ++ks) {
        const float4* p = (const float4*)(T + m * LP + ks * 32 + quad * 8);
        float4 a0 = p[0], a1 = p[1];
        float f[8] = {a0.x, a0.y, a0.z, a0.w, a1.x, a1.y, a1.z, a1.w};
#pragma unroll
        for (int j = 0; j < 8; ++j) {
            unsigned short hh = bf16_hi(f[j]);
            ch[ks][j] = (short)hh;
            cl[ks][j] = (short)bf16_hi(f[j] - bf16_f(hh));
        }
    }

#pragma unroll
    for (int nt = 0; nt < 8; ++nt) {
        f32x4 acc = {0.f, 0.f, 0.f, 0.f};
#pragma unroll
        for (int ks = 0; ks < 4; ++ks) {
            size_t off = ((size_t)(nt * 4 + ks) * 64 + lane) * 8;
            short8 bh = *(const short8*)(w2h + off);
            short8 bl = *(const short8*)(w2l + off);
            acc = __builtin_amdgcn_mfma_f32_16x16x32_bf16(ch[ks], bh, acc, 0, 0, 0);
            acc = __builtin_amdgcn_mfma_f32_16x16x32_bf16(cl[ks], bh, acc, 0, 0, 0);
            acc = __builtin_amdgcn_mfma_f32_16x16x32_bf16(ch[ks], bl, acc, 0, 0, 0);
        }
        float bv = b2[nt * 16 + m];
#pragma unroll
        for (int r = 0; r < 4; ++r) {
            int rr = m0 + quad * 4 + r;
            if (rr < N) {
                float o = acc[r] + bv;
                if (relu2) o = o > 0.f ? o : 0.f;
                C[(size_t)rr * ND + nt * 16 + m] = o;
            }
        }
    }
}

extern "C" void kernel_launch(void* const* d_in, const int* in_sizes, int n_in,
                              void* d_out, int out_size, void* d_ws, size_t ws_size,
                              hipStream_t stream) {
    const float* x = (const float*)d_in[0];
    const int* ei = (const int*)d_in[1];  // int64 in reference -> int32 from harness
    const float* ea = (const float*)d_in[2];
    const float* w1_0 = (const float*)d_in[3];
    const float* b1_0 = (const float*)d_in[4];
    const float* w2_0 = (const float*)d_in[5];
    const float* b2_0 = (const float*)d_in[6];
    const float* we_0 = (const float*)d_in[7];
    const float* be_0 = (const float*)d_in[8];
    const float* w1_1 = (const float*)d_in[9];
    const float* b1_1 = (const float*)d_in[10];
    const float* w2_1 = (const float*)d_in[11];
    const float* b2_1 = (const float*)d_in[12];
    const float* we_1 = (const float*)d_in[13];
    const float* be_1 = (const float*)d_in[14];
    const float* fc1_w = (const float*)d_in[15];
    const float* fc1_b = (const float*)d_in[16];
    const float* fc2_w = (const float*)d_in[17];
    const float* fc2_b = (const float*)d_in[18];

    int N = in_sizes[0] / ND;
    int E = in_sizes[2] / ED;
    int NB = (N + 255) / 256;
    const int NW = 4096;  // agg waves (1024 blocks = 4 blocks/CU, 4 waves/SIMD)
    int NCMAX = N + E / 16 + 16;

    float* bufA = (float*)d_ws;
    int* counts = (int*)(bufA + (size_t)N * ND);
    int* row_start = counts + N;        // N+1
    int* woff = row_start + (N + 1);    // N
    int* bsum = woff + N;               // NB
    int* bofs = bsum + NB;              // NB
    int* bsum2 = bofs + NB;             // NB
    int* bofs2 = bsum2 + NB;            // NB
    int* cofs = bofs2 + NB;             // N+1
    int* cws = cofs + (N + 1);          // NW+1
    int2* cmeta = (int2*)((((uintptr_t)(cws + NW + 1)) + 15) & ~(uintptr_t)15);
    int2* pack = cmeta + NCMAX;
    unsigned short* wfh = (unsigned short*)(pack + E);
    unsigned short* wfl = wfh + 6 * 16384;
    unsigned short* weh = wfl + 6 * 16384;  // 2 * 4096
    unsigned short* xpk = weh + 2 * 4096;   // (N+1) * 256 ushorts = 512B/row
    float* out = (float*)d_out;

    // ---- CSR build + flat chunk list + wave ranges + weight prep ----
    zero_kernel<<<(N + 255) / 256, 256, 0, stream>>>(counts, N);
    hist_kernel<<<(E + 255) / 256, 256, 0, stream>>>(ei, counts, E);
    bsum_kernel<<<NB, 256, 0, stream>>>(counts, bsum, N);
    scan_bsums<<<1, 256, 0, stream>>>(bsum, bofs, row_start + N, NB);
    expand_kernel<<<NB, 256, 0, stream>>>(counts, bofs, row_start, woff, N);
    scatter_kernel<<<(E + 255) / 256, 256, 0, stream>>>(ei, woff, pack, E);
    cbsum_kernel<<<NB, 256, 0, stream>>>(counts, bsum2, N);
    scan_bsums<<<1, 256, 0, stream>>>(bsum2, bofs2, cofs + N, NB);
    cexpand_kernel<<<NB, 256, 0, stream>>>(counts, bofs2, cofs, N);
    cfill_kernel<<<(N + 255) / 256, 256, 0, stream>>>(row_start, cofs, cmeta, N);
    cwrange_kernel<<<(NW + 1 + 255) / 256, 256, 0, stream>>>(cofs, cws, N, NW);
    wprep_kernel<<<dim3(8, 6), 256, 0, stream>>>(w1_0, w2_0, w1_1, w2_1, fc1_w, fc2_w,
                                                 wfh, wfl);
    wprep_we<<<dim3(2, 2), 256, 0, stream>>>(we_0, we_1, weh);

    int gg = ((N + 15) / 16 + 3) / 4;     // fused-MLP blocks (4 waves x 16 rows)
    int gx = ((N + 1) * 16 + 255) / 256;  // xprep blocks

    // ---- layer 0 ----  xprep(x+be0); agg0: x -> out; mlp0: out -> bufA
    xprep_kernel<<<gx, 256, 0, stream>>>(x, be_0, xpk, N);
    agg_mfma<<<NW / 4, 256, 0, stream>>>(x, ea, xpk, weh, cws, cmeta, pack, out, N, E);
    mlp2_mfma<<<gg, 256, 0, stream>>>(out, wfh + 0 * 16384, wfl + 0 * 16384, b1_0,
                                      wfh + 1 * 16384, wfl + 1 * 16384, b2_0, bufA, N, 1);

    // ---- layer 1 ----  xprep(bufA+be1); agg1: bufA -> out; mlp1: out -> bufA
    xprep_kernel<<<gx, 256, 0, stream>>>(bufA, be_1, xpk, N);
    agg_mfma<<<NW / 4, 256, 0, stream>>>(bufA, ea, xpk, weh + 4096, cws, cmeta, pack, out,
                                         N, E);
    mlp2_mfma<<<gg, 256, 0, stream>>>(out, wfh + 2 * 16384, wfl + 2 * 16384, b1_1,
                                      wfh + 3 * 16384, wfl + 3 * 16384, b2_1, bufA, N, 1);

    // ---- head ----  bufA -> out (final)
    mlp2_mfma<<<gg, 256, 0, stream>>>(bufA, wfh + 4 * 16384, wfl + 4 * 16384, fc1_b,
                                      wfh + 5 * 16384, wfl + 5 * 16384, fc2_b, out, N, 0);
}

// Round 5
// 470.519 us; speedup vs baseline: 1.3552x; 1.3552x over previous
//
#include <hip/hip_runtime.h>
#include <stdint.h>

// ---------------------------------------------------------------------------
// GINEncoder: 2x GINEConv(eps=0, MLP 128->128->128, edge_lin 32->128) + head.
//   R12: R4's 2-deep register pipeline SPILLED (VGPR=64 reported vs ~110 live;
//   FETCH +213MB, WRITE +70MB of scratch traffic). Reverted agg to the R3
//   version (93.8us verified). This round attacks launch count (~8-10us per
//   dispatch overhead x 16 launches):
//     - prepwx_kernel: zero + wprep(6 mats) + wprep_we(2) + xprep(layer0)
//       merged via block-role ranges (1 launch instead of 4).
//     - scatter_wrange: scatter + wrange merged (1 instead of 2).
//     - xprep(layer1) FUSED into mlp0's epilogue via the per-wave LDS tile
//       (stage-2 outputs re-read as 8-col granules, be_1 folded, bf16 hi/lo
//       packed) -- deletes one 25.6MB pass + one launch.
//   11 launches total (was 16).
// edge_index is int64 in the reference but harness passes int32.
// ---------------------------------------------------------------------------

#define ND 128
#define ED 32

typedef __attribute__((ext_vector_type(8))) short short8;
typedef __attribute__((ext_vector_type(4))) float f32x4;

__device__ inline unsigned short bf16_hi(float f) {
    union { float f; unsigned u; } v;
    v.f = f;
    return (unsigned short)(v.u >> 16);  // truncation; residual captured by lo
}
__device__ inline float bf16_f(unsigned short h) {
    union { unsigned u; float f; } v;
    v.u = ((unsigned)h) << 16;
    return v.f;
}

__global__ __launch_bounds__(256) void hist_kernel(const int* __restrict__ ei,
                                                   int* __restrict__ counts, int E) {
    int i = blockIdx.x * blockDim.x + threadIdx.x;
    if (i < E) atomicAdd(&counts[ei[E + i]], 1);
}

// ---- two-level parallel scan over counts[N] ----
__global__ __launch_bounds__(256) void bsum_kernel(const int* __restrict__ counts,
                                                   int* __restrict__ bsum, int N) {
    __shared__ int s[256];
    int t = threadIdx.x;
    int i = blockIdx.x * 256 + t;
    s[t] = (i < N) ? counts[i] : 0;
    __syncthreads();
#pragma unroll
    for (int off = 128; off > 0; off >>= 1) {
        if (t < off) s[t] += s[t + off];
        __syncthreads();
    }
    if (t == 0) bsum[blockIdx.x] = s[0];
}

__global__ __launch_bounds__(256) void scan_bsums(const int* __restrict__ bsum,
                                                  int* __restrict__ bofs,
                                                  int* __restrict__ row_start_N, int NB) {
    __shared__ int s[256];
    int t = threadIdx.x;
    int chunk = (NB + 255) >> 8;
    int lo = min(t * chunk, NB);
    int hi = min(lo + chunk, NB);
    int sum = 0;
    for (int i = lo; i < hi; ++i) sum += bsum[i];
    s[t] = sum;
    __syncthreads();
    for (int off = 1; off < 256; off <<= 1) {
        int v = (t >= off) ? s[t - off] : 0;
        __syncthreads();
        s[t] += v;
        __syncthreads();
    }
    int pre = (t == 0) ? 0 : s[t - 1];
    for (int i = lo; i < hi; ++i) {
        bofs[i] = pre;
        pre += bsum[i];
    }
    if (t == 255) *row_start_N = s[255];
}

__global__ __launch_bounds__(256) void expand_kernel(const int* __restrict__ counts,
                                                     const int* __restrict__ bofs,
                                                     int* __restrict__ row_start,
                                                     int* __restrict__ woff, int N) {
    __shared__ int s[256];
    int t = threadIdx.x;
    int i = blockIdx.x * 256 + t;
    int c = (i < N) ? counts[i] : 0;
    s[t] = c;
    __syncthreads();
    for (int off = 1; off < 256; off <<= 1) {
        int v = (t >= off) ? s[t - off] : 0;
        __syncthreads();
        s[t] += v;
        __syncthreads();
    }
    if (i < N) {
        int pre = bofs[blockIdx.x] + s[t] - c;  // exclusive
        row_start[i] = pre;
        woff[i] = pre;
    }
}

// scatter (blocks [0,SB)) + edge-balanced wave ranges (blocks [SB, SB+WB)).
// wstart[w] = min v : row_start[v+1] > w*E/NW  (forced 0 at w=0, N at w=NW).
__global__ __launch_bounds__(256) void scatter_wrange(
    const int* __restrict__ ei, int* __restrict__ woff, int2* __restrict__ pack,
    int E, const int* __restrict__ row_start, int* __restrict__ wstart,
    int N, int NW) {
    int b = blockIdx.x;
    int SB = (E + 255) >> 8;
    if (b < SB) {
        int i = b * 256 + threadIdx.x;
        if (i < E) {
            int d = ei[E + i];
            int p = atomicAdd(&woff[d], 1);
            pack[p] = make_int2(ei[i], i);  // {src, eid}
        }
        return;
    }
    int w = (b - SB) * 256 + threadIdx.x;
    if (w > NW) return;
    if (w == 0) { wstart[0] = 0; return; }
    if (w == NW) { wstart[NW] = N; return; }
    int T = (int)((long long)w * E / NW);
    int lo = 0, hi = N - 1;
    while (lo < hi) {
        int mid = (lo + hi) >> 1;
        if (row_start[mid + 1] > T) hi = mid; else lo = mid + 1;
    }
    wstart[w] = lo;
}

// Merged prep: zero(counts) + wprep(6 weight mats -> bf16 hi/lo B-fragments)
// + wprep_we(2 edge mats -> bf16-hi B-fragments) + xprep(x + be_0 -> xpk).
// Role by linear blockIdx.x ranges.
// wprep fragment order: chunk c = nt*4+ks; lane l holds
// B[k=ks*32+(l>>4)*8+j][n=nt*16+(l&15)], j=0..7.
// xpk layout per row: granule g=kc*4+quad -> [8 hi bf16][8 lo bf16] = 32B;
// row N is the pad sentinel (-29958) so relu(msg)==0 for padded lanes.
__global__ __launch_bounds__(256) void prepwx_kernel(
    int* __restrict__ counts, int N,
    const float* __restrict__ w0, const float* __restrict__ w1,
    const float* __restrict__ w2, const float* __restrict__ w3,
    const float* __restrict__ w4, const float* __restrict__ w5,
    unsigned short* __restrict__ hi, unsigned short* __restrict__ lo,
    const float* __restrict__ e0, const float* __restrict__ e1,
    unsigned short* __restrict__ weh,
    const float* __restrict__ X, const float* __restrict__ be,
    unsigned short* __restrict__ xpk) {
    int b = blockIdx.x;
    int ZB = (N + 255) >> 8;
    if (b < ZB) {  // ---- zero counts ----
        int i = b * 256 + threadIdx.x;
        if (i < N) counts[i] = 0;
        return;
    }
    b -= ZB;
    if (b < 48) {  // ---- wprep: matrix y=b/8, t in [0,2048) ----
        int y = b >> 3;
        int t = (b & 7) * 256 + threadIdx.x;
        const float* W;
        switch (y) {
            case 0: W = w0; break;
            case 1: W = w1; break;
            case 2: W = w2; break;
            case 3: W = w3; break;
            case 4: W = w4; break;
            default: W = w5; break;
        }
        unsigned short* dh = hi + (size_t)y * 16384;
        unsigned short* dl = lo + (size_t)y * 16384;
        int c = t >> 6, l = t & 63;
        int nt = c >> 2, ks = c & 3;
        int n = nt * 16 + (l & 15);
        int kb = ks * 32 + ((l >> 4) << 3);
#pragma unroll
        for (int j = 0; j < 8; ++j) {
            float f = W[(size_t)(kb + j) * ND + n];
            unsigned short h = bf16_hi(f);
            dh[((size_t)c * 64 + l) * 8 + j] = h;
            dl[((size_t)c * 64 + l) * 8 + j] = bf16_hi(f - bf16_f(h));
        }
        return;
    }
    b -= 48;
    if (b < 4) {  // ---- wprep_we: xb=b&1, mat y=b>>1 ----
        int t = threadIdx.x;
        int c = ((b & 1) << 2) + (t >> 6);  // nt 0..7
        int l = t & 63;
        const float* W = (b >> 1) ? e1 : e0;
        unsigned short* dh = weh + (size_t)(b >> 1) * 4096;
        int n = c * 16 + (l & 15);
        int kb = (l >> 4) << 3;
#pragma unroll
        for (int j = 0; j < 8; ++j)
            dh[((size_t)c * 64 + l) * 8 + j] = bf16_hi(W[(size_t)(kb + j) * ND + n]);
        return;
    }
    b -= 4;
    // ---- xprep role: pack (X + be) -> xpk, plus sentinel row N ----
    int t = b * 256 + threadIdx.x;
    int total = (N + 1) * 16;
    if (t >= total) return;
    int v = t >> 4, g = t & 15;
    short8 h, l;
    if (v < N) {
        const float4* p = (const float4*)(X + (size_t)v * ND + g * 8);
        float4 a0 = p[0], a1 = p[1];
        float f[8] = {a0.x, a0.y, a0.z, a0.w, a1.x, a1.y, a1.z, a1.w};
#pragma unroll
        for (int j = 0; j < 8; ++j) {
            float fv = f[j] + be[g * 8 + j];
            unsigned short hh = bf16_hi(fv);
            h[j] = (short)hh;
            l[j] = (short)bf16_hi(fv - bf16_f(hh));
        }
    } else {
#pragma unroll
        for (int j = 0; j < 8; ++j) {
            h[j] = (short)0xC6EA;  // bf16(-29958)
            l[j] = 0;
        }
    }
    unsigned short* dst = xpk + (size_t)t * 16;
    *(short8*)dst = h;
    *(short8*)(dst + 8) = l;
}

// Node-centric MFMA aggregation over a contiguous, edge-balanced node range.
// h[v] = x[v] + sum_{e: dst=v} relu((x[src_e]+be) + ea_e @ we)
// (verbatim R3 kernel: 93.8us verified, VGPR=64, no spill)
__global__ __launch_bounds__(256, 4) void agg_mfma(
    const float* __restrict__ xin, const float* __restrict__ edge_attr,
    const unsigned short* __restrict__ xpk, const unsigned short* __restrict__ bfh,
    const int* __restrict__ row_start, const int* __restrict__ wstart,
    const int2* __restrict__ pack, float* __restrict__ hout, int N, int E) {
    int lane = threadIdx.x & 63;
    int gw = (blockIdx.x * blockDim.x + threadIdx.x) >> 6;
    int m = lane & 15;
    int quad = lane >> 4;

    // we fragments (bf16-hi), held in registers for the whole kernel
    short8 bh[8];
#pragma unroll
    for (int nt = 0; nt < 8; ++nt)
        bh[nt] = *(const short8*)(bfh + ((size_t)nt * 64 + lane) * 8);

    // identity B-fragments: for tile parity q, B[k'=quad*8+j][n'=m] = (k'==q*16+m)
    short8 idf[2];
#pragma unroll
    for (int q = 0; q < 2; ++q)
#pragma unroll
        for (int j = 0; j < 8; ++j)
            idf[q][j] = (quad * 8 + j == q * 16 + m) ? (short)0x3F80 : (short)0;

    int col0 = quad * 32 + m;
    int col1 = col0 + 16;

    int v_lo = wstart[gw];
    int v_hi = wstart[gw + 1];
    if (v_lo >= v_hi) return;

    int beg = row_start[v_lo];
    // pack prefetch: pk2 always holds entries for the next chunk position.
    int2 pk2 = pack[min(beg + m, E - 1)];

    for (int v = v_lo; v < v_hi; ++v) {
        int end = row_start[v + 1];
        // residual loads overlap the gather latency below
        float res0 = xin[(size_t)v * ND + col0];
        float res1 = xin[(size_t)v * ND + col1];
        float part[8];
#pragma unroll
        for (int nt = 0; nt < 8; ++nt) part[nt] = 0.f;

        for (int base = beg; base < end; base += 16) {
            int2 pk = pk2;
            // next chunk: same node (base+16) or next node's first chunk (end)
            int nxt = (base + 16 < end) ? base + 16 : end;
            pk2 = pack[min(nxt + m, E - 1)];

            int rem = end - base;  // >= 1
            int s = (m < rem) ? pk.x : N;  // sentinel row kills pad lanes in relu

            // ---- batched loads: 8 dwordx4 x-fragments + 2 dwordx4 ea ----
            const unsigned short* xr = xpk + ((size_t)s * 16 + quad) * 16;
            short8 xh[4], xl[4];
#pragma unroll
            for (int kc = 0; kc < 4; ++kc) {
                xh[kc] = *(const short8*)(xr + kc * 64);
                xl[kc] = *(const short8*)(xr + kc * 64 + 8);
            }
            const float4* ar = (const float4*)(edge_attr + (size_t)pk.y * ED + quad * 8);
            float4 a0 = ar[0], a1 = ar[1];

            // ea A-fragment split hi/lo (exact)
            float af[8] = {a0.x, a0.y, a0.z, a0.w, a1.x, a1.y, a1.z, a1.w};
            short8 ah, al;
#pragma unroll
            for (int j = 0; j < 8; ++j) {
                unsigned short h = bf16_hi(af[j]);
                ah[j] = (short)h;
                al[j] = (short)bf16_hi(af[j] - bf16_f(h));
            }

#pragma unroll
            for (int nt = 0; nt < 8; ++nt) {
                f32x4 a = {0.f, 0.f, 0.f, 0.f};
                a = __builtin_amdgcn_mfma_f32_16x16x32_bf16(ah, bh[nt], a, 0, 0, 0);
                a = __builtin_amdgcn_mfma_f32_16x16x32_bf16(al, bh[nt], a, 0, 0, 0);
                a = __builtin_amdgcn_mfma_f32_16x16x32_bf16(xh[nt >> 1], idf[nt & 1], a,
                                                            0, 0, 0);
                a = __builtin_amdgcn_mfma_f32_16x16x32_bf16(xl[nt >> 1], idf[nt & 1], a,
                                                            0, 0, 0);
#pragma unroll
                for (int r = 0; r < 4; ++r)
                    part[nt] += fmaxf(a[r], 0.f);  // be already inside xpk
            }
        }
        // reduce over quads (cols live in lanes m, m+16, m+32, m+48)
#pragma unroll
        for (int nt = 0; nt < 8; ++nt) {
            float p = part[nt];
            p += __shfl_xor(p, 16, 64);
            p += __shfl_xor(p, 32, 64);
            part[nt] = p;
        }
        // quad q writes cols of tiles 2q, 2q+1
        float o0 = quad == 0 ? part[0] : quad == 1 ? part[2] : quad == 2 ? part[4] : part[6];
        float o1 = quad == 0 ? part[1] : quad == 1 ? part[3] : quad == 2 ? part[5] : part[7];
        hout[(size_t)v * ND + col0] = res0 + o0;
        hout[(size_t)v * ND + col1] = res1 + o1;
        beg = end;
    }
}

// Fused pair of GEMMs: C = maybe_relu2( relu(A@W1+b1) @ W2 + b2 ).
// Wave = 16 rows; intermediate goes through a per-wave LDS tile (132-pad rows).
// If xpk != nullptr, also emits xpk fragments of (C + ben) via the (dead by
// then) LDS tile -- fuses the next layer's xprep pass into this kernel.
#define LP 132  // padded LDS row stride (floats); 132*4B keeps 16B alignment
__global__ __launch_bounds__(256, 4) void mlp2_mfma(
    const float* __restrict__ A,
    const unsigned short* __restrict__ w1h, const unsigned short* __restrict__ w1l,
    const float* __restrict__ b1,
    const unsigned short* __restrict__ w2h, const unsigned short* __restrict__ w2l,
    const float* __restrict__ b2,
    float* __restrict__ C, int N, int relu2,
    const float* __restrict__ ben, unsigned short* __restrict__ xpk) {
    __shared__ float tile[4][16 * LP];
    int lane = threadIdx.x & 63;
    int wave = threadIdx.x >> 6;
    int gw = blockIdx.x * 4 + wave;
    int m0 = gw * 16;
    if (m0 >= N) return;
    int m = lane & 15;
    int quad = lane >> 4;
    float* T = tile[wave];

    // ---- stage 1: load A rows, split hi/lo ----
    int row = m0 + m;
    bool rok = row < N;
    short8 ah[4], al[4];
#pragma unroll
    for (int ks = 0; ks < 4; ++ks) {
        float f[8];
        if (rok) {
            const float4* p = (const float4*)(A + (size_t)row * ND + ks * 32 + quad * 8);
            float4 a0 = p[0], a1 = p[1];
            f[0] = a0.x; f[1] = a0.y; f[2] = a0.z; f[3] = a0.w;
            f[4] = a1.x; f[5] = a1.y; f[6] = a1.z; f[7] = a1.w;
        } else {
#pragma unroll
            for (int j = 0; j < 8; ++j) f[j] = 0.f;
        }
#pragma unroll
        for (int j = 0; j < 8; ++j) {
            unsigned short hh = bf16_hi(f[j]);
            ah[ks][j] = (short)hh;
            al[ks][j] = (short)bf16_hi(f[j] - bf16_f(hh));
        }
    }

    // GEMM1 -> bias + relu -> LDS tile (C/D layout: col=lane&15, row=quad*4+r)
#pragma unroll
    for (int nt = 0; nt < 8; ++nt) {
        f32x4 acc = {0.f, 0.f, 0.f, 0.f};
#pragma unroll
        for (int ks = 0; ks < 4; ++ks) {
            size_t off = ((size_t)(nt * 4 + ks) * 64 + lane) * 8;
            short8 bh = *(const short8*)(w1h + off);
            short8 bl = *(const short8*)(w1l + off);
            acc = __builtin_amdgcn_mfma_f32_16x16x32_bf16(ah[ks], bh, acc, 0, 0, 0);
            acc = __builtin_amdgcn_mfma_f32_16x16x32_bf16(al[ks], bh, acc, 0, 0, 0);
            acc = __builtin_amdgcn_mfma_f32_16x16x32_bf16(ah[ks], bl, acc, 0, 0, 0);
        }
        float bv = b1[nt * 16 + m];
#pragma unroll
        for (int r = 0; r < 4; ++r) {
            float o = acc[r] + bv;
            o = o > 0.f ? o : 0.f;
            T[(quad * 4 + r) * LP + nt * 16 + m] = o;
        }
    }

    // ---- stage 2: rows from LDS as A-fragments (same wave -> lgkmcnt wait) ----
    short8 ch[4], cl[4];
#pragma unroll
    for (int ks = 0; ks < 4; ++ks) {
        const float4* p = (const float4*)(T + m * LP + ks * 32 + quad * 8);
        float4 a0 = p[0], a1 = p[1];
        float f[8] = {a0.x, a0.y, a0.z, a0.w, a1.x, a1.y, a1.z, a1.w};
#pragma unroll
        for (int j = 0; j < 8; ++j) {
            unsigned short hh = bf16_hi(f[j]);
            ch[ks][j] = (short)hh;
            cl[ks][j] = (short)bf16_hi(f[j] - bf16_f(hh));
        }
    }

#pragma unroll
    for (int nt = 0; nt < 8; ++nt) {
        f32x4 acc = {0.f, 0.f, 0.f, 0.f};
#pragma unroll
        for (int ks = 0; ks < 4; ++ks) {
            size_t off = ((size_t)(nt * 4 + ks) * 64 + lane) * 8;
            short8 bh = *(const short8*)(w2h + off);
            short8 bl = *(const short8*)(w2l + off);
            acc = __builtin_amdgcn_mfma_f32_16x16x32_bf16(ch[ks], bh, acc, 0, 0, 0);
            acc = __builtin_amdgcn_mfma_f32_16x16x32_bf16(cl[ks], bh, acc, 0, 0, 0);
            acc = __builtin_amdgcn_mfma_f32_16x16x32_bf16(ch[ks], bl, acc, 0, 0, 0);
        }
        float bv = b2[nt * 16 + m];
#pragma unroll
        for (int r = 0; r < 4; ++r) {
            int rr = m0 + quad * 4 + r;
            float o = acc[r] + bv;
            if (relu2) o = o > 0.f ? o : 0.f;
            if (rr < N) C[(size_t)rr * ND + nt * 16 + m] = o;
            if (xpk) T[(quad * 4 + r) * LP + nt * 16 + m] = o;  // stash for pack
        }
    }

    // ---- fused xprep: pack (C + ben) rows -> xpk granules ----
    // (stage-1 T contents are dead; stage-2 reads completed before overwrite)
    if (xpk) {
#pragma unroll
        for (int i = 0; i < 4; ++i) {
            int task = lane + 64 * i;  // 256 tasks = 16 rows x 16 granules
            int rl = task >> 4;
            int g = task & 15;
            int rr = m0 + rl;
            if (rr < N) {
                const float4* p = (const float4*)(T + rl * LP + g * 8);
                float4 a0 = p[0], a1 = p[1];
                float f[8] = {a0.x, a0.y, a0.z, a0.w, a1.x, a1.y, a1.z, a1.w};
                short8 h, l;
#pragma unroll
                for (int j = 0; j < 8; ++j) {
                    float fv = f[j] + ben[g * 8 + j];
                    unsigned short hh = bf16_hi(fv);
                    h[j] = (short)hh;
                    l[j] = (short)bf16_hi(fv - bf16_f(hh));
                }
                unsigned short* dst = xpk + ((size_t)rr * 16 + g) * 16;
                *(short8*)dst = h;
                *(short8*)(dst + 8) = l;
            }
        }
    }
}

extern "C" void kernel_launch(void* const* d_in, const int* in_sizes, int n_in,
                              void* d_out, int out_size, void* d_ws, size_t ws_size,
                              hipStream_t stream) {
    const float* x = (const float*)d_in[0];
    const int* ei = (const int*)d_in[1];  // int64 in reference -> int32 from harness
    const float* ea = (const float*)d_in[2];
    const float* w1_0 = (const float*)d_in[3];
    const float* b1_0 = (const float*)d_in[4];
    const float* w2_0 = (const float*)d_in[5];
    const float* b2_0 = (const float*)d_in[6];
    const float* we_0 = (const float*)d_in[7];
    const float* be_0 = (const float*)d_in[8];
    const float* w1_1 = (const float*)d_in[9];
    const float* b1_1 = (const float*)d_in[10];
    const float* w2_1 = (const float*)d_in[11];
    const float* b2_1 = (const float*)d_in[12];
    const float* we_1 = (const float*)d_in[13];
    const float* be_1 = (const float*)d_in[14];
    const float* fc1_w = (const float*)d_in[15];
    const float* fc1_b = (const float*)d_in[16];
    const float* fc2_w = (const float*)d_in[17];
    const float* fc2_b = (const float*)d_in[18];

    int N = in_sizes[0] / ND;
    int E = in_sizes[2] / ED;
    int NB = (N + 255) / 256;
    const int NW = 4096;  // agg waves (1024 blocks = 4 blocks/CU, 4 waves/SIMD)

    float* bufA = (float*)d_ws;
    int* counts = (int*)(bufA + (size_t)N * ND);
    int* row_start = counts + N;        // N+1
    int* woff = row_start + (N + 1);    // N
    int* bsum = woff + N;               // NB
    int* bofs = bsum + NB;              // NB
    int* wstart = bofs + NB;            // NW+1
    int2* pack = (int2*)((((uintptr_t)(wstart + NW + 1)) + 15) & ~(uintptr_t)15);
    unsigned short* wfh = (unsigned short*)(pack + E);
    unsigned short* wfl = wfh + 6 * 16384;
    unsigned short* weh = wfl + 6 * 16384;  // 2 * 4096
    unsigned short* xpk = weh + 2 * 4096;   // (N+1) * 256 ushorts = 512B/row
    float* out = (float*)d_out;

    int ZB = (N + 255) / 256;
    int gx = ((N + 1) * 16 + 255) / 256;   // xprep role blocks
    int SB = (E + 255) / 256;              // scatter role blocks
    int WB = (NW + 1 + 255) / 256;         // wrange role blocks
    int gg = ((N + 15) / 16 + 3) / 4;      // fused-MLP blocks (4 waves x 16 rows)

    // ---- prep: 6 launches (was 9) ----
    prepwx_kernel<<<ZB + 48 + 4 + gx, 256, 0, stream>>>(
        counts, N, w1_0, w2_0, w1_1, w2_1, fc1_w, fc2_w, wfh, wfl,
        we_0, we_1, weh, x, be_0, xpk);
    hist_kernel<<<(E + 255) / 256, 256, 0, stream>>>(ei, counts, E);
    bsum_kernel<<<NB, 256, 0, stream>>>(counts, bsum, N);
    scan_bsums<<<1, 256, 0, stream>>>(bsum, bofs, row_start + N, NB);
    expand_kernel<<<NB, 256, 0, stream>>>(counts, bofs, row_start, woff, N);
    scatter_wrange<<<SB + WB, 256, 0, stream>>>(ei, woff, pack, E, row_start, wstart,
                                                N, NW);

    // ---- layer 0 ----  agg0: x -> out; mlp0: out -> bufA (+ xpk for layer 1)
    agg_mfma<<<NW / 4, 256, 0, stream>>>(x, ea, xpk, weh, row_start, wstart, pack, out,
                                         N, E);
    mlp2_mfma<<<gg, 256, 0, stream>>>(out, wfh + 0 * 16384, wfl + 0 * 16384, b1_0,
                                      wfh + 1 * 16384, wfl + 1 * 16384, b2_0, bufA, N, 1,
                                      be_1, xpk);

    // ---- layer 1 ----  agg1: bufA -> out; mlp1: out -> bufA
    agg_mfma<<<NW / 4, 256, 0, stream>>>(bufA, ea, xpk, weh + 4096, row_start, wstart,
                                         pack, out, N, E);
    mlp2_mfma<<<gg, 256, 0, stream>>>(out, wfh + 2 * 16384, wfl + 2 * 16384, b1_1,
                                      wfh + 3 * 16384, wfl + 3 * 16384, b2_1, bufA, N, 1,
                                      nullptr, nullptr);

    // ---- head ----  bufA -> out (final)
    mlp2_mfma<<<gg, 256, 0, stream>>>(bufA, wfh + 4 * 16384, wfl + 4 * 16384, fc1_b,
                                      wfh + 5 * 16384, wfl + 5 * 16384, fc2_b, out, N, 0,
                                      nullptr, nullptr);
}